// Round 1
// baseline (1397.363 us; speedup 1.0000x reference)
//
#include <hip/hip_runtime.h>

// ---------------------------------------------------------------------------
// Problem constants (from reference): B=2048, NS=8, S=8, H=512, WH=1, WK=32,
// RH=4, RK=32, T=NS+S=16.  M = B*8 = 16384 rows for every GEMM.
// ---------------------------------------------------------------------------
#define Bb   2048
#define Mrows 16384   // B*8
#define Hd   512

typedef float  f32x4  __attribute__((ext_vector_type(4)));
typedef __bf16 bf16x8 __attribute__((ext_vector_type(8)));
typedef unsigned short us8 __attribute__((ext_vector_type(8)));

__device__ __forceinline__ unsigned short f2bf(float f) {
    unsigned int u = __builtin_bit_cast(unsigned int, f);
    u = u + 0x7FFFu + ((u >> 16) & 1u);   // round-to-nearest-even
    return (unsigned short)(u >> 16);
}
__device__ __forceinline__ float bf2f(unsigned short h) {
    unsigned int u = ((unsigned int)h) << 16;
    return __builtin_bit_cast(float, u);
}

// ---------------------------------------------------------------------------
// Workspace layout (bytes).  Peak ~212 MB with aliasing (lifetimes verified):
//   RV_OUT aliases [UT_RELU..CTX1), CTX2 aliases [CTX1+4MB..GATES+20MB)
// ---------------------------------------------------------------------------
#define MB (1024ull*1024ull)
#define OFF_WQ   0ull
#define OFF_WK   32768ull
#define OFF_WV   65536ull
#define OFF_WO   589824ull
#define OFF_UT   1114112ull
#define OFF_UG   1638400ull
#define OFF_RQ   2686976ull
#define OFF_RK   2818048ull
#define OFF_RV   2949120ull
#define OFF_RO   5046272ull
#define OFF_HS    (8*MB)
#define OFF_MEM   (24*MB)
#define OFF_UTR   (40*MB)
#define OFF_MEAN  (56*MB)
#define OFF_Q1    (60*MB)
#define OFF_K1    (62*MB)
#define OFF_V1    (66*MB)
#define OFF_CTX1  (100*MB)
#define OFF_KK    (116*MB)
#define OFF_TMW   (132*MB)
#define OFF_GATES (148*MB)
#define OFF_MNB   (180*MB)
#define OFF_Q2    (196*MB)
#define OFF_K2    (204*MB)
#define OFF_RVO   (40*MB)    // alias: UT_RELU/MEAN/Q1/K1/V1/CTX1[0:4MB] all dead
#define OFF_CTX2  (104*MB)   // alias: CTX1[4:]/KK/TMW/GATES[0:20MB] all dead

// ---------------------------------------------------------------------------
// Cast f32 -> bf16, 12 segments in one kernel (blockIdx.y = segment)
// ---------------------------------------------------------------------------
struct CastSeg { const float* src; unsigned short* dst; int n4; };
struct CastParams { CastSeg seg[12]; };

__global__ __launch_bounds__(256) void cast_all(CastParams p) {
    CastSeg s = p.seg[blockIdx.y];
    int stride = gridDim.x * blockDim.x;
    for (int i = blockIdx.x * blockDim.x + threadIdx.x; i < s.n4; i += stride) {
        float4 v = reinterpret_cast<const float4*>(s.src)[i];
        ushort4 o;
        o.x = f2bf(v.x); o.y = f2bf(v.y); o.z = f2bf(v.z); o.w = f2bf(v.w);
        reinterpret_cast<ushort4*>(s.dst)[i] = o;
    }
}

// ---------------------------------------------------------------------------
// Generic MFMA GEMM:  C(M,N) = A(M,K)bf16 . W(N,K)bf16^T + bias, epilogue MODE
// block = 4 waves; wave w owns rows [bm*64+16w, +16), cols [bn*16*TN, +16*TN)
// MODE: 0 f32  1 bf16  2 relu->bf16  3 sigmoid->bf16  4 tanh->bf16
//       5 f32 + row remap (k concat)  6 bf16 + row remap (v concat)
//       7 f32 + extra (residual h_s)
// ---------------------------------------------------------------------------
template<int TN, int MODE>
__global__ __launch_bounds__(256) void gemm_k(
    const unsigned short* __restrict__ A, const unsigned short* __restrict__ W,
    const float* __restrict__ bias, void* __restrict__ out,
    const float* __restrict__ extra, int N, int K, int ldo, int remap_off)
{
    constexpr int BN = 16 * TN;
    const int tiles_n = N / BN;
    const int bm = blockIdx.x / tiles_n;
    const int bn = blockIdx.x % tiles_n;
    const int wave = threadIdx.x >> 6;
    const int lane = threadIdx.x & 63;
    const int row0 = bm * 64 + wave * 16;
    const int col0 = bn * BN;
    const int lrow = lane & 15;
    const int lk   = (lane >> 4) << 3;   // k offset within 32-wide K step

    f32x4 acc[TN] = {};
    const unsigned short* ap  = A + (size_t)(row0 + lrow) * K + lk;
    const unsigned short* wp0 = W + (size_t)(col0 + lrow) * K + lk;

    for (int ks = 0; ks < K; ks += 32) {
        bf16x8 af = __builtin_bit_cast(bf16x8,
                        *reinterpret_cast<const us8*>(ap + ks));
        #pragma unroll
        for (int t = 0; t < TN; t++) {
            bf16x8 bfm = __builtin_bit_cast(bf16x8,
                        *reinterpret_cast<const us8*>(wp0 + (size_t)t * 16 * K + ks));
            acc[t] = __builtin_amdgcn_mfma_f32_16x16x32_bf16(af, bfm, acc[t], 0, 0, 0);
        }
    }

    const int crow = (lane >> 4) * 2 * 2;      // (lane>>4)*4
    #pragma unroll
    for (int t = 0; t < TN; t++) {
        int col = col0 + t * 16 + (lane & 15);
        float bv = bias[col];
        #pragma unroll
        for (int r = 0; r < 4; r++) {
            int row = row0 + crow + r;
            float v = acc[t][r] + bv;
            if (MODE == 0) {
                ((float*)out)[(size_t)row * ldo + col] = v;
            } else if (MODE == 1) {
                ((unsigned short*)out)[(size_t)row * ldo + col] = f2bf(v);
            } else if (MODE == 2) {
                ((unsigned short*)out)[(size_t)row * ldo + col] = f2bf(fmaxf(v, 0.f));
            } else if (MODE == 3) {
                ((unsigned short*)out)[(size_t)row * ldo + col] = f2bf(1.f / (1.f + expf(-v)));
            } else if (MODE == 4) {
                ((unsigned short*)out)[(size_t)row * ldo + col] = f2bf(tanhf(v));
            } else if (MODE == 5) {
                int rr = ((row >> 3) << 4) + (row & 7) + remap_off;
                ((float*)out)[(size_t)rr * ldo + col] = v;
            } else if (MODE == 6) {
                int rr = ((row >> 3) << 4) + (row & 7) + remap_off;
                ((unsigned short*)out)[(size_t)rr * ldo + col] = f2bf(v);
            } else if (MODE == 7) {
                ((float*)out)[(size_t)row * ldo + col] = v + extra[(size_t)row * ldo + col];
            }
        }
    }
}

// ---------------------------------------------------------------------------
// inputs_mean = relu(ut(h_s)).mean over NS=8 rows per batch
// ---------------------------------------------------------------------------
__global__ __launch_bounds__(256) void mean_kernel(
    const unsigned short* __restrict__ UTR, float* __restrict__ MEAN)
{
    int idx = blockIdx.x * blockDim.x + threadIdx.x;   // 2048*512
    if (idx >= Bb * Hd) return;
    int b = idx >> 9, j = idx & 511;
    float s = 0.f;
    #pragma unroll
    for (int r = 0; r < 8; r++)
        s += bf2f(UTR[((size_t)(b * 8 + r) << 9) + j]);
    MEAN[idx] = s * 0.125f;
}

// kk = inputs_mean + tanh(mem)   -> bf16
__global__ __launch_bounds__(256) void kk_kernel(
    const float* __restrict__ MEAN, const float* __restrict__ mem,
    unsigned short* __restrict__ KK)
{
    int idx = blockIdx.x * blockDim.x + threadIdx.x;   // 16384*512
    int m = idx >> 9;
    int bj = ((m >> 3) << 9) + (idx & 511);
    KK[idx] = f2bf(MEAN[bj] + tanhf(mem[idx]));
}

// mem_new = sig(ig)*tanh(mem_write) + sig(fg)*mem  (gates already sigmoided)
__global__ __launch_bounds__(256) void memnew_kernel(
    const unsigned short* __restrict__ GATES, const unsigned short* __restrict__ TMW,
    const float* __restrict__ mem, float* __restrict__ out_mem,
    unsigned short* __restrict__ MNB)
{
    int idx = blockIdx.x * blockDim.x + threadIdx.x;   // 16384*512
    int m = idx >> 9, j = idx & 511;
    float ig = bf2f(GATES[(size_t)m * 1024 + j]);
    float fg = bf2f(GATES[(size_t)m * 1024 + 512 + j]);
    float v  = ig * bf2f(TMW[idx]) + fg * mem[idx];
    out_mem[idx] = v;
    MNB[idx] = f2bf(v);
}

// ---------------------------------------------------------------------------
// Attention 1: per batch, q(8,32) k(16,32) v(16,512) -> ctx(8,512) bf16
// ---------------------------------------------------------------------------
__global__ __launch_bounds__(256) void attn1_kernel(
    const float* __restrict__ Q1, const float* __restrict__ K1,
    const unsigned short* __restrict__ V1, unsigned short* __restrict__ CTX1)
{
    int b = blockIdx.x, t = threadIdx.x;
    __shared__ float q[8][32], k[16][32], pr[8][16];
    q[t >> 5][t & 31] = Q1[(size_t)b * 256 + t];
    k[t >> 5][t & 31]       = K1[(size_t)b * 512 + t];
    k[8 + (t >> 5)][t & 31] = K1[(size_t)b * 512 + 256 + t];
    __syncthreads();
    if (t < 128) {
        int s = t >> 4, tt = t & 15;
        float acc = 0.f;
        #pragma unroll
        for (int i = 0; i < 32; i++) acc += q[s][i] * k[tt][i];
        pr[s][tt] = acc * 0.17677669529663687f;   // 1/sqrt(32)
    }
    __syncthreads();
    if (t < 8) {
        float m = -1e30f;
        for (int i = 0; i < 16; i++) m = fmaxf(m, pr[t][i]);
        float e[16], sum = 0.f;
        for (int i = 0; i < 16; i++) { e[i] = expf(pr[t][i] - m); sum += e[i]; }
        float inv = 1.f / sum;
        for (int i = 0; i < 16; i++) pr[t][i] = e[i] * inv;
    }
    __syncthreads();
    int s = t >> 5, d0 = (t & 31) * 16;
    float a[16];
    #pragma unroll
    for (int i = 0; i < 16; i++) a[i] = 0.f;
    for (int tt = 0; tt < 16; tt++) {
        float p = pr[s][tt];
        const unsigned short* vp = V1 + ((size_t)(b * 16 + tt)) * 512 + d0;
        us8 v0 = *reinterpret_cast<const us8*>(vp);
        us8 v1 = *reinterpret_cast<const us8*>(vp + 8);
        #pragma unroll
        for (int i = 0; i < 8; i++) a[i]     += p * bf2f(v0[i]);
        #pragma unroll
        for (int i = 0; i < 8; i++) a[8 + i] += p * bf2f(v1[i]);
    }
    us8 o0, o1;
    #pragma unroll
    for (int i = 0; i < 8; i++) { o0[i] = f2bf(a[i]); o1[i] = f2bf(a[8 + i]); }
    unsigned short* cp = CTX1 + ((size_t)(b * 8 + s)) * 512 + d0;
    *reinterpret_cast<us8*>(cp) = o0;
    *reinterpret_cast<us8*>(cp + 8) = o1;
}

// ---------------------------------------------------------------------------
// Attention 2: per batch, 4 heads: q(8,32) k(8,32) v(8,512) -> ctx(8,2048)
// ---------------------------------------------------------------------------
__global__ __launch_bounds__(256) void attn2_kernel(
    const float* __restrict__ Q2, const float* __restrict__ K2,
    const unsigned short* __restrict__ V2, unsigned short* __restrict__ CTX2)
{
    int b = blockIdx.x, t = threadIdx.x;
    __shared__ float q[8][128], k[8][128], pr[4][8][8];
    for (int i = t; i < 1024; i += 256) {
        q[i >> 7][i & 127] = Q2[(size_t)b * 1024 + i];
        k[i >> 7][i & 127] = K2[(size_t)b * 1024 + i];
    }
    __syncthreads();
    {
        int h = t >> 6, n = (t >> 3) & 7, s = t & 7;
        float acc = 0.f;
        #pragma unroll
        for (int i = 0; i < 32; i++) acc += q[n][h * 32 + i] * k[s][h * 32 + i];
        pr[h][n][s] = acc * 0.17677669529663687f;
    }
    __syncthreads();
    if (t < 32) {
        int h = t >> 3, n = t & 7;
        float m = -1e30f;
        for (int i = 0; i < 8; i++) m = fmaxf(m, pr[h][n][i]);
        float e[8], sum = 0.f;
        for (int i = 0; i < 8; i++) { e[i] = expf(pr[h][n][i] - m); sum += e[i]; }
        float inv = 1.f / sum;
        for (int i = 0; i < 8; i++) pr[h][n][i] = e[i] * inv;
    }
    __syncthreads();
    int n = t >> 5, d0 = (t & 31) * 16;
    for (int h = 0; h < 4; h++) {
        float a[16];
        #pragma unroll
        for (int i = 0; i < 16; i++) a[i] = 0.f;
        for (int s = 0; s < 8; s++) {
            float p = pr[h][n][s];
            const unsigned short* vp = V2 + ((size_t)(b * 8 + s)) * 2048 + h * 512 + d0;
            us8 v0 = *reinterpret_cast<const us8*>(vp);
            us8 v1 = *reinterpret_cast<const us8*>(vp + 8);
            #pragma unroll
            for (int i = 0; i < 8; i++) a[i]     += p * bf2f(v0[i]);
            #pragma unroll
            for (int i = 0; i < 8; i++) a[8 + i] += p * bf2f(v1[i]);
        }
        us8 o0, o1;
        #pragma unroll
        for (int i = 0; i < 8; i++) { o0[i] = f2bf(a[i]); o1[i] = f2bf(a[8 + i]); }
        unsigned short* cp = CTX2 + ((size_t)(b * 8 + n)) * 2048 + h * 512 + d0;
        *reinterpret_cast<us8*>(cp) = o0;
        *reinterpret_cast<us8*>(cp + 8) = o1;
    }
}

// ---------------------------------------------------------------------------
extern "C" void kernel_launch(void* const* d_in, const int* in_sizes, int n_in,
                              void* d_out, int out_size, void* d_ws, size_t ws_size,
                              hipStream_t stream)
{
    const float* h_s  = (const float*)d_in[0];
    const float* mem  = (const float*)d_in[1];
    const float* wq_w = (const float*)d_in[2];  const float* wq_b = (const float*)d_in[3];
    const float* wk_w = (const float*)d_in[4];  const float* wk_b = (const float*)d_in[5];
    const float* wv_w = (const float*)d_in[6];  const float* wv_b = (const float*)d_in[7];
    const float* wo_w = (const float*)d_in[8];  const float* wo_b = (const float*)d_in[9];
    const float* ut_w = (const float*)d_in[10]; const float* ut_b = (const float*)d_in[11];
    const float* ug_w = (const float*)d_in[12]; const float* ug_b = (const float*)d_in[13];
    const float* rq_w = (const float*)d_in[14]; const float* rq_b = (const float*)d_in[15];
    const float* rk_w = (const float*)d_in[16]; const float* rk_b = (const float*)d_in[17];
    const float* rv_w = (const float*)d_in[18]; const float* rv_b = (const float*)d_in[19];
    const float* ro_w = (const float*)d_in[20]; const float* ro_b = (const float*)d_in[21];

    char* ws = (char*)d_ws;
    unsigned short* WQb = (unsigned short*)(ws + OFF_WQ);
    unsigned short* WKb = (unsigned short*)(ws + OFF_WK);
    unsigned short* WVb = (unsigned short*)(ws + OFF_WV);
    unsigned short* WOb = (unsigned short*)(ws + OFF_WO);
    unsigned short* UTb = (unsigned short*)(ws + OFF_UT);
    unsigned short* UGb = (unsigned short*)(ws + OFF_UG);
    unsigned short* RQb = (unsigned short*)(ws + OFF_RQ);
    unsigned short* RKb = (unsigned short*)(ws + OFF_RK);
    unsigned short* RVb = (unsigned short*)(ws + OFF_RV);
    unsigned short* ROb = (unsigned short*)(ws + OFF_RO);
    unsigned short* HSb  = (unsigned short*)(ws + OFF_HS);
    unsigned short* MEMb = (unsigned short*)(ws + OFF_MEM);
    unsigned short* UTR  = (unsigned short*)(ws + OFF_UTR);
    float*          MEAN = (float*)(ws + OFF_MEAN);
    float*          Q1   = (float*)(ws + OFF_Q1);
    float*          K1   = (float*)(ws + OFF_K1);
    unsigned short* V1   = (unsigned short*)(ws + OFF_V1);
    unsigned short* CTX1 = (unsigned short*)(ws + OFF_CTX1);
    unsigned short* KKb  = (unsigned short*)(ws + OFF_KK);
    unsigned short* TMW  = (unsigned short*)(ws + OFF_TMW);
    unsigned short* GATES= (unsigned short*)(ws + OFF_GATES);
    unsigned short* MNB  = (unsigned short*)(ws + OFF_MNB);
    float*          Q2   = (float*)(ws + OFF_Q2);
    float*          K2   = (float*)(ws + OFF_K2);
    unsigned short* RVO  = (unsigned short*)(ws + OFF_RVO);
    unsigned short* CTX2 = (unsigned short*)(ws + OFF_CTX2);

    float* out   = (float*)d_out;            // h_out (16384,512)
    float* out_m = out + (size_t)Mrows * Hd; // mem_new (16384,512)

    // 1) cast inputs + weights to bf16
    CastParams cp;
    cp.seg[0]  = { h_s,  HSb,  (Mrows * Hd) / 4 };
    cp.seg[1]  = { mem,  MEMb, (Mrows * Hd) / 4 };
    cp.seg[2]  = { wq_w, WQb,  (32 * 512) / 4 };
    cp.seg[3]  = { wk_w, WKb,  (32 * 512) / 4 };
    cp.seg[4]  = { wv_w, WVb,  (512 * 512) / 4 };
    cp.seg[5]  = { wo_w, WOb,  (512 * 512) / 4 };
    cp.seg[6]  = { ut_w, UTb,  (512 * 512) / 4 };
    cp.seg[7]  = { ug_w, UGb,  (1024 * 512) / 4 };
    cp.seg[8]  = { rq_w, RQb,  (128 * 512) / 4 };
    cp.seg[9]  = { rk_w, RKb,  (128 * 512) / 4 };
    cp.seg[10] = { rv_w, RVb,  (2048 * 512) / 4 };
    cp.seg[11] = { ro_w, ROb,  (512 * 2048) / 4 };
    cast_all<<<dim3(2048, 12), 256, 0, stream>>>(cp);

    // 2) stage-1 GEMMs (depend only on h_s / mem)
    gemm_k<4,2><<<2048, 256, 0, stream>>>(HSb,  UTb, ut_b, UTR, nullptr, 512, 512, 512, 0);
    gemm_k<4,0><<<512,  256, 0, stream>>>(HSb,  RQb, rq_b, Q2,  nullptr, 128, 512, 128, 0);
    gemm_k<2,5><<<256,  256, 0, stream>>>(HSb,  WKb, wk_b, K1,  nullptr,  32, 512,  32, 0);
    gemm_k<4,6><<<2048, 256, 0, stream>>>(HSb,  WVb, wv_b, V1,  nullptr, 512, 512, 512, 0);
    gemm_k<2,0><<<256,  256, 0, stream>>>(MEMb, WQb, wq_b, Q1,  nullptr,  32, 512,  32, 0);
    gemm_k<2,5><<<256,  256, 0, stream>>>(MEMb, WKb, wk_b, K1,  nullptr,  32, 512,  32, 8);
    gemm_k<4,6><<<2048, 256, 0, stream>>>(MEMb, WVb, wv_b, V1,  nullptr, 512, 512, 512, 8);

    // 3) mean + kk
    mean_kernel<<<4096, 256, 0, stream>>>(UTR, MEAN);
    kk_kernel<<<32768, 256, 0, stream>>>(MEAN, mem, KKb);

    // 4) attention 1 -> ctx1
    attn1_kernel<<<Bb, 256, 0, stream>>>(Q1, K1, V1, CTX1);

    // 5) wo (-> tanh(mem_write)) and ug (-> sigmoid gates)
    gemm_k<4,4><<<2048, 256, 0, stream>>>(CTX1, WOb, wo_b, TMW,   nullptr,  512, 512,  512, 0);
    gemm_k<4,3><<<4096, 256, 0, stream>>>(KKb,  UGb, ug_b, GATES, nullptr, 1024, 512, 1024, 0);

    // 6) mem_new (writes d_out second half + bf16 copy)
    memnew_kernel<<<32768, 256, 0, stream>>>(GATES, TMW, mem, out_m, MNB);

    // 7) rk, rv on mem_new
    gemm_k<4,0><<<512,  256, 0, stream>>>(MNB, RKb, rk_b, K2,  nullptr,  128, 512,  128, 0);
    gemm_k<4,1><<<8192, 256, 0, stream>>>(MNB, RVb, rv_b, RVO, nullptr, 2048, 512, 2048, 0);

    // 8) attention 2 -> ctx2
    attn2_kernel<<<Bb, 256, 0, stream>>>(Q2, K2, RVO, CTX2);

    // 9) ro + residual -> h_out (d_out first half)
    gemm_k<4,7><<<2048, 256, 0, stream>>>(CTX2, ROb, ro_b, out, h_s, 512, 2048, 512, 0);

    (void)in_sizes; (void)n_in; (void)out_size; (void)ws_size;
}

// Round 2
// 554.076 us; speedup vs baseline: 2.5220x; 2.5220x over previous
//
#include <hip/hip_runtime.h>

// ---------------------------------------------------------------------------
// Problem constants: B=2048, NS=8, S=8, H=512, WH=1, WK=32, RH=4, RK=32, T=16.
// ---------------------------------------------------------------------------
#define Bb   2048
#define Mrows 16384   // B*8
#define Hd   512

typedef float  f32x4  __attribute__((ext_vector_type(4)));
typedef __bf16 bf16x8 __attribute__((ext_vector_type(8)));
typedef unsigned short us8 __attribute__((ext_vector_type(8)));

__device__ __forceinline__ unsigned short f2bf(float f) {
    unsigned int u = __builtin_bit_cast(unsigned int, f);
    u = u + 0x7FFFu + ((u >> 16) & 1u);   // round-to-nearest-even
    return (unsigned short)(u >> 16);
}
__device__ __forceinline__ float bf2f(unsigned short h) {
    unsigned int u = ((unsigned int)h) << 16;
    return __builtin_bit_cast(float, u);
}

// ---------------------------------------------------------------------------
// Workspace layout (bytes); aliases verified by lifetime in round 1 (passed).
// ---------------------------------------------------------------------------
#define MB (1024ull*1024ull)
#define OFF_WQ   0ull
#define OFF_WK   32768ull
#define OFF_WV   65536ull
#define OFF_WO   589824ull
#define OFF_UT   1114112ull
#define OFF_UG   1638400ull
#define OFF_RQ   2686976ull
#define OFF_RK   2818048ull
#define OFF_RV   2949120ull
#define OFF_RO   5046272ull
#define OFF_HS    (8*MB)
#define OFF_MEM   (24*MB)
#define OFF_UTR   (40*MB)
#define OFF_MEAN  (56*MB)
#define OFF_Q1    (60*MB)
#define OFF_K1    (62*MB)
#define OFF_V1    (66*MB)
#define OFF_CTX1  (100*MB)
#define OFF_KK    (116*MB)
#define OFF_TMW   (132*MB)
#define OFF_GATES (148*MB)
#define OFF_MNB   (180*MB)
#define OFF_Q2    (196*MB)
#define OFF_K2    (204*MB)
#define OFF_RVO   (40*MB)    // alias: UTR/MEAN/Q1/K1/V1/CTX1[0:4MB] dead by then
#define OFF_CTX2  (104*MB)   // alias: CTX1[4:]/KK/TMW/GATES[0:20MB] dead by then

// ---------------------------------------------------------------------------
// Cast f32 -> bf16, 12 segments in one kernel
// ---------------------------------------------------------------------------
struct CastSeg { const float* src; unsigned short* dst; int n4; };
struct CastParams { CastSeg seg[12]; };

__global__ __launch_bounds__(256) void cast_all(CastParams p) {
    CastSeg s = p.seg[blockIdx.y];
    int stride = gridDim.x * blockDim.x;
    for (int i = blockIdx.x * blockDim.x + threadIdx.x; i < s.n4; i += stride) {
        float4 v = reinterpret_cast<const float4*>(s.src)[i];
        ushort4 o;
        o.x = f2bf(v.x); o.y = f2bf(v.y); o.z = f2bf(v.z); o.w = f2bf(v.w);
        reinterpret_cast<ushort4*>(s.dst)[i] = o;
    }
}

// ---------------------------------------------------------------------------
// Shared epilogue.  MODE: 0 f32  1 bf16  2 relu->bf16  3 sigmoid->bf16
// 4 tanh->bf16  5 f32+row-remap  6 bf16+row-remap  7 f32+residual
// ---------------------------------------------------------------------------
template<int MODE>
__device__ __forceinline__ void store_c(void* out, const float* extra, int row,
                                        int col, int ldo, int remap_off, float v) {
    if (MODE == 0) {
        ((float*)out)[(size_t)row * ldo + col] = v;
    } else if (MODE == 1) {
        ((unsigned short*)out)[(size_t)row * ldo + col] = f2bf(v);
    } else if (MODE == 2) {
        ((unsigned short*)out)[(size_t)row * ldo + col] = f2bf(fmaxf(v, 0.f));
    } else if (MODE == 3) {
        ((unsigned short*)out)[(size_t)row * ldo + col] = f2bf(1.f / (1.f + expf(-v)));
    } else if (MODE == 4) {
        ((unsigned short*)out)[(size_t)row * ldo + col] = f2bf(tanhf(v));
    } else if (MODE == 5) {
        int rr = ((row >> 3) << 4) + (row & 7) + remap_off;
        ((float*)out)[(size_t)rr * ldo + col] = v;
    } else if (MODE == 6) {
        int rr = ((row >> 3) << 4) + (row & 7) + remap_off;
        ((unsigned short*)out)[(size_t)rr * ldo + col] = f2bf(v);
    } else if (MODE == 7) {
        ((float*)out)[(size_t)row * ldo + col] = v + extra[(size_t)row * ldo + col];
    }
}

// ---------------------------------------------------------------------------
// Big LDS-staged GEMM: C(M,N) = A(M,K) . W(N,K)^T + bias, bf16 in, MFMA.
// Block tile 128x128, BK=64, 4 waves in 2x2, wave tile 64x64 (4x4 fragments).
// LDS tiles [128][64] bf16 with 16B-chunk XOR swizzle (chunk ^= row&7) so the
// column-slice ds_read_b128 (16 lanes, 16 consecutive rows) is conflict-free.
// Reg-staged: global loads for tile k+1 issued under compute of tile k.
// ---------------------------------------------------------------------------
template<int K, int MODE>
__global__ __launch_bounds__(256, 2) void gemm_big(
    const unsigned short* __restrict__ A, const unsigned short* __restrict__ W,
    const float* __restrict__ bias, void* __restrict__ out,
    const float* __restrict__ extra, int N, int ldo, int remap_off)
{
    constexpr int NT = K / 64;
    __shared__ __align__(16) unsigned short As[128 * 64];
    __shared__ __align__(16) unsigned short Bs[128 * 64];

    const int tiles_n = N >> 7;
    const int bm = (int)blockIdx.x / tiles_n;
    const int bn = (int)blockIdx.x - bm * tiles_n;
    const int t = threadIdx.x;
    const int wave = t >> 6, lane = t & 63;
    const int wr = (wave >> 1) * 64;       // wave row offset in tile
    const int wc = (wave & 1) * 64;        // wave col offset in tile
    const int lrow = lane & 15;
    const int lkh  = lane >> 4;            // 0..3

    // staging: thread t covers 16B chunk (t&7) of rows (t>>3)+32*i, i=0..3
    const int srow = t >> 3;               // 0..31
    const int sch  = t & 7;                // 0..7
    const unsigned short* ag = A + (size_t)(bm * 128 + srow) * K + sch * 8;
    const unsigned short* bg = W + (size_t)(bn * 128 + srow) * K + sch * 8;

    int wofs[4];
    #pragma unroll
    for (int i = 0; i < 4; i++) {
        int row = srow + 32 * i;
        wofs[i] = row * 64 + ((sch ^ (row & 7)) << 3);
    }

    // fragment ds_read offsets (swizzled)
    int aof[4][2], bof[4][2];
    #pragma unroll
    for (int m = 0; m < 4; m++) {
        int ra = wr + m * 16 + lrow;
        int rb = wc + m * 16 + lrow;
        #pragma unroll
        for (int kk = 0; kk < 2; kk++) {
            int kc = kk * 4 + lkh;
            aof[m][kk] = ra * 64 + ((kc ^ (ra & 7)) << 3);
            bof[m][kk] = rb * 64 + ((kc ^ (rb & 7)) << 3);
        }
    }

    us8 ar[4], br[4];
    f32x4 acc[4][4] = {};

    #pragma unroll
    for (int i = 0; i < 4; i++) {
        ar[i] = *reinterpret_cast<const us8*>(ag + (size_t)(32 * i) * K);
        br[i] = *reinterpret_cast<const us8*>(bg + (size_t)(32 * i) * K);
    }

    for (int kt = 0; kt < NT; ++kt) {
        // stage regs -> LDS (swizzled)
        #pragma unroll
        for (int i = 0; i < 4; i++) {
            *reinterpret_cast<us8*>(&As[wofs[i]]) = ar[i];
            *reinterpret_cast<us8*>(&Bs[wofs[i]]) = br[i];
        }
        __syncthreads();
        // issue next tile's global loads (hidden under compute)
        if (kt + 1 < NT) {
            const unsigned short* ag2 = ag + (kt + 1) * 64;
            const unsigned short* bg2 = bg + (kt + 1) * 64;
            #pragma unroll
            for (int i = 0; i < 4; i++) {
                ar[i] = *reinterpret_cast<const us8*>(ag2 + (size_t)(32 * i) * K);
                br[i] = *reinterpret_cast<const us8*>(bg2 + (size_t)(32 * i) * K);
            }
        }
        // compute: 2 k-substeps x 4x4 fragments
        #pragma unroll
        for (int kk = 0; kk < 2; kk++) {
            bf16x8 af[4], bf_[4];
            #pragma unroll
            for (int m = 0; m < 4; m++)
                af[m] = __builtin_bit_cast(bf16x8,
                            *reinterpret_cast<const us8*>(&As[aof[m][kk]]));
            #pragma unroll
            for (int n = 0; n < 4; n++)
                bf_[n] = __builtin_bit_cast(bf16x8,
                            *reinterpret_cast<const us8*>(&Bs[bof[n][kk]]));
            #pragma unroll
            for (int m = 0; m < 4; m++)
                #pragma unroll
                for (int n = 0; n < 4; n++)
                    acc[m][n] = __builtin_amdgcn_mfma_f32_16x16x32_bf16(
                                    af[m], bf_[n], acc[m][n], 0, 0, 0);
        }
        __syncthreads();
    }

    // epilogue
    #pragma unroll
    for (int n = 0; n < 4; n++) {
        int col = bn * 128 + wc + n * 16 + lrow;
        float bv = bias[col];
        #pragma unroll
        for (int m = 0; m < 4; m++) {
            #pragma unroll
            for (int r = 0; r < 4; r++) {
                int row = bm * 128 + wr + m * 16 + lkh * 4 + r;
                store_c<MODE>(out, extra, row, col, ldo, remap_off,
                              acc[m][n][r] + bv);
            }
        }
    }
}

// ---------------------------------------------------------------------------
// Small GEMM (N=32): direct-global fragments, compile-time K for unrolling.
// ---------------------------------------------------------------------------
template<int TN, int MODE, int K>
__global__ __launch_bounds__(256) void gemm_small(
    const unsigned short* __restrict__ A, const unsigned short* __restrict__ W,
    const float* __restrict__ bias, void* __restrict__ out,
    const float* __restrict__ extra, int N, int ldo, int remap_off)
{
    constexpr int BN = 16 * TN;
    const int tiles_n = N / BN;
    const int bm = blockIdx.x / tiles_n;
    const int bn = blockIdx.x % tiles_n;
    const int wave = threadIdx.x >> 6;
    const int lane = threadIdx.x & 63;
    const int row0 = bm * 64 + wave * 16;
    const int col0 = bn * BN;
    const int lrow = lane & 15;
    const int lk   = (lane >> 4) << 3;

    f32x4 acc[TN] = {};
    const unsigned short* ap  = A + (size_t)(row0 + lrow) * K + lk;
    const unsigned short* wp0 = W + (size_t)(col0 + lrow) * K + lk;

    #pragma unroll 4
    for (int ks = 0; ks < K; ks += 32) {
        bf16x8 af = __builtin_bit_cast(bf16x8,
                        *reinterpret_cast<const us8*>(ap + ks));
        #pragma unroll
        for (int tt = 0; tt < TN; tt++) {
            bf16x8 bfm = __builtin_bit_cast(bf16x8,
                        *reinterpret_cast<const us8*>(wp0 + (size_t)tt * 16 * K + ks));
            acc[tt] = __builtin_amdgcn_mfma_f32_16x16x32_bf16(af, bfm, acc[tt], 0, 0, 0);
        }
    }

    #pragma unroll
    for (int tt = 0; tt < TN; tt++) {
        int col = col0 + tt * 16 + lrow;
        float bv = bias[col];
        #pragma unroll
        for (int r = 0; r < 4; r++) {
            int row = row0 + (lane >> 4) * 4 + r;
            store_c<MODE>(out, extra, row, col, ldo, remap_off, acc[tt][r] + bv);
        }
    }
}

// ---------------------------------------------------------------------------
// inputs_mean = relu(ut(h_s)).mean over NS=8 rows per batch
// ---------------------------------------------------------------------------
__global__ __launch_bounds__(256) void mean_kernel(
    const unsigned short* __restrict__ UTR, float* __restrict__ MEAN)
{
    int idx = blockIdx.x * blockDim.x + threadIdx.x;   // 2048*512
    if (idx >= Bb * Hd) return;
    int b = idx >> 9, j = idx & 511;
    float s = 0.f;
    #pragma unroll
    for (int r = 0; r < 8; r++)
        s += bf2f(UTR[((size_t)(b * 8 + r) << 9) + j]);
    MEAN[idx] = s * 0.125f;
}

// kk = inputs_mean + tanh(mem)   -> bf16
__global__ __launch_bounds__(256) void kk_kernel(
    const float* __restrict__ MEAN, const float* __restrict__ mem,
    unsigned short* __restrict__ KK)
{
    int idx = blockIdx.x * blockDim.x + threadIdx.x;   // 16384*512
    int m = idx >> 9;
    int bj = ((m >> 3) << 9) + (idx & 511);
    KK[idx] = f2bf(MEAN[bj] + tanhf(mem[idx]));
}

// mem_new = sig(ig)*tanh(mem_write) + sig(fg)*mem  (gates already sigmoided)
__global__ __launch_bounds__(256) void memnew_kernel(
    const unsigned short* __restrict__ GATES, const unsigned short* __restrict__ TMW,
    const float* __restrict__ mem, float* __restrict__ out_mem,
    unsigned short* __restrict__ MNB)
{
    int idx = blockIdx.x * blockDim.x + threadIdx.x;   // 16384*512
    int m = idx >> 9, j = idx & 511;
    float ig = bf2f(GATES[(size_t)m * 1024 + j]);
    float fg = bf2f(GATES[(size_t)m * 1024 + 512 + j]);
    float v  = ig * bf2f(TMW[idx]) + fg * mem[idx];
    out_mem[idx] = v;
    MNB[idx] = f2bf(v);
}

// ---------------------------------------------------------------------------
// Attention 1: per batch, q(8,32) k(16,32) v(16,512) -> ctx(8,512) bf16
// ---------------------------------------------------------------------------
__global__ __launch_bounds__(256) void attn1_kernel(
    const float* __restrict__ Q1, const float* __restrict__ K1,
    const unsigned short* __restrict__ V1, unsigned short* __restrict__ CTX1)
{
    int b = blockIdx.x, t = threadIdx.x;
    __shared__ float q[8][32], k[16][32], pr[8][16];
    q[t >> 5][t & 31] = Q1[(size_t)b * 256 + t];
    k[t >> 5][t & 31]       = K1[(size_t)b * 512 + t];
    k[8 + (t >> 5)][t & 31] = K1[(size_t)b * 512 + 256 + t];
    __syncthreads();
    if (t < 128) {
        int s = t >> 4, tt = t & 15;
        float acc = 0.f;
        #pragma unroll
        for (int i = 0; i < 32; i++) acc += q[s][i] * k[tt][i];
        pr[s][tt] = acc * 0.17677669529663687f;   // 1/sqrt(32)
    }
    __syncthreads();
    if (t < 8) {
        float m = -1e30f;
        for (int i = 0; i < 16; i++) m = fmaxf(m, pr[t][i]);
        float e[16], sum = 0.f;
        for (int i = 0; i < 16; i++) { e[i] = expf(pr[t][i] - m); sum += e[i]; }
        float inv = 1.f / sum;
        for (int i = 0; i < 16; i++) pr[t][i] = e[i] * inv;
    }
    __syncthreads();
    int s = t >> 5, d0 = (t & 31) * 16;
    float a[16];
    #pragma unroll
    for (int i = 0; i < 16; i++) a[i] = 0.f;
    for (int tt = 0; tt < 16; tt++) {
        float p = pr[s][tt];
        const unsigned short* vp = V1 + ((size_t)(b * 16 + tt)) * 512 + d0;
        us8 v0 = *reinterpret_cast<const us8*>(vp);
        us8 v1 = *reinterpret_cast<const us8*>(vp + 8);
        #pragma unroll
        for (int i = 0; i < 8; i++) a[i]     += p * bf2f(v0[i]);
        #pragma unroll
        for (int i = 0; i < 8; i++) a[8 + i] += p * bf2f(v1[i]);
    }
    us8 o0, o1;
    #pragma unroll
    for (int i = 0; i < 8; i++) { o0[i] = f2bf(a[i]); o1[i] = f2bf(a[8 + i]); }
    unsigned short* cp = CTX1 + ((size_t)(b * 8 + s)) * 512 + d0;
    *reinterpret_cast<us8*>(cp) = o0;
    *reinterpret_cast<us8*>(cp + 8) = o1;
}

// ---------------------------------------------------------------------------
// Attention 2: per batch, 4 heads: q(8,32) k(8,32) v(8,512) -> ctx(8,2048)
// ---------------------------------------------------------------------------
__global__ __launch_bounds__(256) void attn2_kernel(
    const float* __restrict__ Q2, const float* __restrict__ K2,
    const unsigned short* __restrict__ V2, unsigned short* __restrict__ CTX2)
{
    int b = blockIdx.x, t = threadIdx.x;
    __shared__ float q[8][128], k[8][128], pr[4][8][8];
    for (int i = t; i < 1024; i += 256) {
        q[i >> 7][i & 127] = Q2[(size_t)b * 1024 + i];
        k[i >> 7][i & 127] = K2[(size_t)b * 1024 + i];
    }
    __syncthreads();
    {
        int h = t >> 6, n = (t >> 3) & 7, s = t & 7;
        float acc = 0.f;
        #pragma unroll
        for (int i = 0; i < 32; i++) acc += q[n][h * 32 + i] * k[s][h * 32 + i];
        pr[h][n][s] = acc * 0.17677669529663687f;
    }
    __syncthreads();
    if (t < 32) {
        int h = t >> 3, n = t & 7;
        float m = -1e30f;
        for (int i = 0; i < 8; i++) m = fmaxf(m, pr[h][n][i]);
        float e[8], sum = 0.f;
        for (int i = 0; i < 8; i++) { e[i] = expf(pr[h][n][i] - m); sum += e[i]; }
        float inv = 1.f / sum;
        for (int i = 0; i < 8; i++) pr[h][n][i] = e[i] * inv;
    }
    __syncthreads();
    int n = t >> 5, d0 = (t & 31) * 16;
    for (int h = 0; h < 4; h++) {
        float a[16];
        #pragma unroll
        for (int i = 0; i < 16; i++) a[i] = 0.f;
        for (int s = 0; s < 8; s++) {
            float p = pr[h][n][s];
            const unsigned short* vp = V2 + ((size_t)(b * 8 + s)) * 2048 + h * 512 + d0;
            us8 v0 = *reinterpret_cast<const us8*>(vp);
            us8 v1 = *reinterpret_cast<const us8*>(vp + 8);
            #pragma unroll
            for (int i = 0; i < 8; i++) a[i]     += p * bf2f(v0[i]);
            #pragma unroll
            for (int i = 0; i < 8; i++) a[8 + i] += p * bf2f(v1[i]);
        }
        us8 o0, o1;
        #pragma unroll
        for (int i = 0; i < 8; i++) { o0[i] = f2bf(a[i]); o1[i] = f2bf(a[8 + i]); }
        unsigned short* cp = CTX2 + ((size_t)(b * 8 + n)) * 2048 + h * 512 + d0;
        *reinterpret_cast<us8*>(cp) = o0;
        *reinterpret_cast<us8*>(cp + 8) = o1;
    }
}

// ---------------------------------------------------------------------------
extern "C" void kernel_launch(void* const* d_in, const int* in_sizes, int n_in,
                              void* d_out, int out_size, void* d_ws, size_t ws_size,
                              hipStream_t stream)
{
    const float* h_s  = (const float*)d_in[0];
    const float* mem  = (const float*)d_in[1];
    const float* wq_w = (const float*)d_in[2];  const float* wq_b = (const float*)d_in[3];
    const float* wk_w = (const float*)d_in[4];  const float* wk_b = (const float*)d_in[5];
    const float* wv_w = (const float*)d_in[6];  const float* wv_b = (const float*)d_in[7];
    const float* wo_w = (const float*)d_in[8];  const float* wo_b = (const float*)d_in[9];
    const float* ut_w = (const float*)d_in[10]; const float* ut_b = (const float*)d_in[11];
    const float* ug_w = (const float*)d_in[12]; const float* ug_b = (const float*)d_in[13];
    const float* rq_w = (const float*)d_in[14]; const float* rq_b = (const float*)d_in[15];
    const float* rk_w = (const float*)d_in[16]; const float* rk_b = (const float*)d_in[17];
    const float* rv_w = (const float*)d_in[18]; const float* rv_b = (const float*)d_in[19];
    const float* ro_w = (const float*)d_in[20]; const float* ro_b = (const float*)d_in[21];

    char* ws = (char*)d_ws;
    unsigned short* WQb = (unsigned short*)(ws + OFF_WQ);
    unsigned short* WKb = (unsigned short*)(ws + OFF_WK);
    unsigned short* WVb = (unsigned short*)(ws + OFF_WV);
    unsigned short* WOb = (unsigned short*)(ws + OFF_WO);
    unsigned short* UTb = (unsigned short*)(ws + OFF_UT);
    unsigned short* UGb = (unsigned short*)(ws + OFF_UG);
    unsigned short* RQb = (unsigned short*)(ws + OFF_RQ);
    unsigned short* RKb = (unsigned short*)(ws + OFF_RK);
    unsigned short* RVb = (unsigned short*)(ws + OFF_RV);
    unsigned short* ROb = (unsigned short*)(ws + OFF_RO);
    unsigned short* HSb  = (unsigned short*)(ws + OFF_HS);
    unsigned short* MEMb = (unsigned short*)(ws + OFF_MEM);
    unsigned short* UTR  = (unsigned short*)(ws + OFF_UTR);
    float*          MEAN = (float*)(ws + OFF_MEAN);
    float*          Q1   = (float*)(ws + OFF_Q1);
    float*          K1   = (float*)(ws + OFF_K1);
    unsigned short* V1   = (unsigned short*)(ws + OFF_V1);
    unsigned short* CTX1 = (unsigned short*)(ws + OFF_CTX1);
    unsigned short* KKb  = (unsigned short*)(ws + OFF_KK);
    unsigned short* TMW  = (unsigned short*)(ws + OFF_TMW);
    unsigned short* GATES= (unsigned short*)(ws + OFF_GATES);
    unsigned short* MNB  = (unsigned short*)(ws + OFF_MNB);
    float*          Q2   = (float*)(ws + OFF_Q2);
    float*          K2   = (float*)(ws + OFF_K2);
    unsigned short* RVO  = (unsigned short*)(ws + OFF_RVO);
    unsigned short* CTX2 = (unsigned short*)(ws + OFF_CTX2);

    float* out   = (float*)d_out;            // h_out (16384,512)
    float* out_m = out + (size_t)Mrows * Hd; // mem_new (16384,512)

    // 1) cast inputs + weights to bf16
    CastParams cp;
    cp.seg[0]  = { h_s,  HSb,  (Mrows * Hd) / 4 };
    cp.seg[1]  = { mem,  MEMb, (Mrows * Hd) / 4 };
    cp.seg[2]  = { wq_w, WQb,  (32 * 512) / 4 };
    cp.seg[3]  = { wk_w, WKb,  (32 * 512) / 4 };
    cp.seg[4]  = { wv_w, WVb,  (512 * 512) / 4 };
    cp.seg[5]  = { wo_w, WOb,  (512 * 512) / 4 };
    cp.seg[6]  = { ut_w, UTb,  (512 * 512) / 4 };
    cp.seg[7]  = { ug_w, UGb,  (1024 * 512) / 4 };
    cp.seg[8]  = { rq_w, RQb,  (128 * 512) / 4 };
    cp.seg[9]  = { rk_w, RKb,  (128 * 512) / 4 };
    cp.seg[10] = { rv_w, RVb,  (2048 * 512) / 4 };
    cp.seg[11] = { ro_w, ROb,  (512 * 2048) / 4 };
    cast_all<<<dim3(2048, 12), 256, 0, stream>>>(cp);

    // 2) stage-1 GEMMs (depend only on h_s / mem)
    gemm_big<512,2><<<512,  256, 0, stream>>>(HSb,  UTb, ut_b, UTR, nullptr, 512, 512, 0);
    gemm_big<512,0><<<128,  256, 0, stream>>>(HSb,  RQb, rq_b, Q2,  nullptr, 128, 128, 0);
    gemm_small<2,5,512><<<256, 256, 0, stream>>>(HSb, WKb, wk_b, K1, nullptr, 32, 32, 0);
    gemm_big<512,6><<<1024, 256, 0, stream>>>(HSb,  WVb, wv_b, V1,  nullptr, 512, 512, 0);
    gemm_small<2,0,512><<<256, 256, 0, stream>>>(MEMb, WQb, wq_b, Q1, nullptr, 32, 32, 0);
    gemm_small<2,5,512><<<256, 256, 0, stream>>>(MEMb, WKb, wk_b, K1, nullptr, 32, 32, 8);
    gemm_big<512,6><<<1024, 256, 0, stream>>>(MEMb, WVb, wv_b, V1,  nullptr, 512, 512, 8);

    // 3) mean + kk
    mean_kernel<<<4096, 256, 0, stream>>>(UTR, MEAN);
    kk_kernel<<<32768, 256, 0, stream>>>(MEAN, mem, KKb);

    // 4) attention 1 -> ctx1
    attn1_kernel<<<Bb, 256, 0, stream>>>(Q1, K1, V1, CTX1);

    // 5) wo (-> tanh(mem_write)) and ug (-> sigmoid gates)
    gemm_big<512,4><<<512,  256, 0, stream>>>(CTX1, WOb, wo_b, TMW,   nullptr,  512,  512, 0);
    gemm_big<512,3><<<1024, 256, 0, stream>>>(KKb,  UGb, ug_b, GATES, nullptr, 1024, 1024, 0);

    // 6) mem_new (writes d_out second half + bf16 copy)
    memnew_kernel<<<32768, 256, 0, stream>>>(GATES, TMW, mem, out_m, MNB);

    // 7) rk, rv on mem_new
    gemm_big<512,0><<<128,  256, 0, stream>>>(MNB, RKb, rk_b, K2,  nullptr,  128,  128, 0);
    gemm_big<512,1><<<2048, 256, 0, stream>>>(MNB, RVb, rv_b, RVO, nullptr, 2048, 2048, 0);

    // 8) attention 2 -> ctx2
    attn2_kernel<<<Bb, 256, 0, stream>>>(Q2, K2, RVO, CTX2);

    // 9) ro + residual -> h_out (d_out first half)
    gemm_big<2048,7><<<512, 256, 0, stream>>>(CTX2, ROb, ro_b, out, h_s, 512, 512, 0);

    (void)in_sizes; (void)n_in; (void)out_size; (void)ws_size;
}

// Round 3
// 516.542 us; speedup vs baseline: 2.7052x; 1.0727x over previous
//
#include <hip/hip_runtime.h>

// ---------------------------------------------------------------------------
// Problem constants: B=2048, NS=8, S=8, H=512, WH=1, WK=32, RH=4, RK=32, T=16.
// ---------------------------------------------------------------------------
#define Bb   2048
#define Mrows 16384   // B*8
#define Hd   512

typedef float  f32x4  __attribute__((ext_vector_type(4)));
typedef __bf16 bf16x8 __attribute__((ext_vector_type(8)));
typedef unsigned short us8 __attribute__((ext_vector_type(8)));

__device__ __forceinline__ unsigned short f2bf(float f) {
    unsigned int u = __builtin_bit_cast(unsigned int, f);
    u = u + 0x7FFFu + ((u >> 16) & 1u);   // round-to-nearest-even
    return (unsigned short)(u >> 16);
}
__device__ __forceinline__ float bf2f(unsigned short h) {
    unsigned int u = ((unsigned int)h) << 16;
    return __builtin_bit_cast(float, u);
}

// async global->LDS DMA, 16B per lane; lds dest = wave-uniform base + lane*16
__device__ __forceinline__ void gload_lds16(const unsigned short* g, void* lds) {
    __builtin_amdgcn_global_load_lds(
        (const __attribute__((address_space(1))) unsigned int*)g,
        (__attribute__((address_space(3))) unsigned int*)lds,
        16, 0, 0);
}

// ---------------------------------------------------------------------------
// Workspace layout (bytes); aliases verified by lifetime (rounds 1-2 passed).
// ---------------------------------------------------------------------------
#define MB (1024ull*1024ull)
#define OFF_WQ   0ull
#define OFF_WK   32768ull
#define OFF_WV   65536ull
#define OFF_WO   589824ull
#define OFF_UT   1114112ull
#define OFF_UG   1638400ull
#define OFF_RQ   2686976ull
#define OFF_RK   2818048ull
#define OFF_RV   2949120ull
#define OFF_RO   5046272ull
#define OFF_HS    (8*MB)
#define OFF_MEM   (24*MB)
#define OFF_UTR   (40*MB)
#define OFF_MEAN  (56*MB)
#define OFF_Q1    (60*MB)
#define OFF_K1    (62*MB)
#define OFF_V1    (66*MB)
#define OFF_CTX1  (100*MB)
#define OFF_KK    (116*MB)
#define OFF_TMW   (132*MB)
#define OFF_GATES (148*MB)
#define OFF_MNB   (180*MB)
#define OFF_Q2    (196*MB)
#define OFF_K2    (204*MB)
#define OFF_RVO   (40*MB)    // alias: UTR/MEAN/Q1/K1/V1/CTX1[0:4MB] dead by then
#define OFF_CTX2  (104*MB)   // alias: CTX1[4:]/KK/TMW/GATES[0:20MB] dead by then

// ---------------------------------------------------------------------------
// Cast f32 -> bf16, 12 segments in one kernel
// ---------------------------------------------------------------------------
struct CastSeg { const float* src; unsigned short* dst; int n4; };
struct CastParams { CastSeg seg[12]; };

__global__ __launch_bounds__(256) void cast_all(CastParams p) {
    CastSeg s = p.seg[blockIdx.y];
    int stride = gridDim.x * blockDim.x;
    for (int i = blockIdx.x * blockDim.x + threadIdx.x; i < s.n4; i += stride) {
        float4 v = reinterpret_cast<const float4*>(s.src)[i];
        ushort4 o;
        o.x = f2bf(v.x); o.y = f2bf(v.y); o.z = f2bf(v.z); o.w = f2bf(v.w);
        reinterpret_cast<ushort4*>(s.dst)[i] = o;
    }
}

// ---------------------------------------------------------------------------
// Shared epilogue.  MODE: 0 f32  1 bf16  2 relu->bf16  3 sigmoid->bf16
// 4 tanh->bf16  5 f32+row-remap  6 bf16+row-remap  7 f32+residual
// ---------------------------------------------------------------------------
template<int MODE>
__device__ __forceinline__ void store_c(void* out, const float* extra, int row,
                                        int col, int ldo, int remap_off, float v) {
    if (MODE == 0) {
        ((float*)out)[(size_t)row * ldo + col] = v;
    } else if (MODE == 1) {
        ((unsigned short*)out)[(size_t)row * ldo + col] = f2bf(v);
    } else if (MODE == 2) {
        ((unsigned short*)out)[(size_t)row * ldo + col] = f2bf(fmaxf(v, 0.f));
    } else if (MODE == 3) {
        ((unsigned short*)out)[(size_t)row * ldo + col] = f2bf(1.f / (1.f + expf(-v)));
    } else if (MODE == 4) {
        ((unsigned short*)out)[(size_t)row * ldo + col] = f2bf(tanhf(v));
    } else if (MODE == 5) {
        int rr = ((row >> 3) << 4) + (row & 7) + remap_off;
        ((float*)out)[(size_t)rr * ldo + col] = v;
    } else if (MODE == 6) {
        int rr = ((row >> 3) << 4) + (row & 7) + remap_off;
        ((unsigned short*)out)[(size_t)rr * ldo + col] = f2bf(v);
    } else if (MODE == 7) {
        ((float*)out)[(size_t)row * ldo + col] = v + extra[(size_t)row * ldo + col];
    }
}

// ---------------------------------------------------------------------------
// Big GEMM: C(M,N) = A(M,K).W(N,K)^T + bias.  128x128 tile, BK=64, 4 waves
// (2x2), wave tile 64x64 = 4x4 fragments of 16x16x32 MFMA.
// Staging: global_load_lds dwordx4 (async DMA, no VGPR roundtrip), LDS dest
// linear; the 16B-chunk XOR swizzle (slot = kchunk ^ (row&7)) is applied by
// permuting the GLOBAL source address per lane (m173 pattern), so ds_read_b128
// fragment reads stay conflict-free (verified: SQ_LDS_BANK_CONFLICT==0).
// Grid = (M/128)*(N/128) exact, with bijective XCD-chunk swizzle so all bn
// tiles of one bm run on the same XCD -> A panel is L2-resident (T1).
// ---------------------------------------------------------------------------
template<int K, int MODE>
__global__ __launch_bounds__(256) void gemm_big(
    const unsigned short* __restrict__ A, const unsigned short* __restrict__ W,
    const float* __restrict__ bias, void* __restrict__ out,
    const float* __restrict__ extra, int N, int ldo, int remap_off)
{
    constexpr int NT = K / 64;
    __shared__ __align__(16) unsigned short As[128 * 64];
    __shared__ __align__(16) unsigned short Bs[128 * 64];

    // XCD-chunk swizzle (grid is always a multiple of 8)
    const int nwg = (int)gridDim.x;
    const int swz = ((int)blockIdx.x & 7) * (nwg >> 3) + ((int)blockIdx.x >> 3);
    const int tiles_n = N >> 7;
    const int bm = swz / tiles_n;
    const int bn = swz - bm * tiles_n;

    const int t = threadIdx.x;
    const int wave = t >> 6, lane = t & 63;
    const int wr = (wave >> 1) * 64;       // wave row offset in tile
    const int wc = (wave & 1) * 64;        // wave col offset in tile
    const int lrow = lane & 15;
    const int lkh  = lane >> 4;            // 0..3

    // staging sources: call j of wave covers chunk c = wave*256 + j*64 + lane
    // chunk c -> LDS byte c*16 (linear); holds logical k-chunk (c&7)^(row&7)
    const unsigned short* ga[4];
    const unsigned short* gb[4];
    #pragma unroll
    for (int j = 0; j < 4; j++) {
        int c   = wave * 256 + j * 64 + lane;
        int row = c >> 3;
        int kl  = (c & 7) ^ (row & 7);
        ga[j] = A + (size_t)(bm * 128 + row) * K + kl * 8;
        gb[j] = W + (size_t)(bn * 128 + row) * K + kl * 8;
    }

    // fragment ds_read offsets (elements, swizzled)
    int aof[4][2], bof[4][2];
    #pragma unroll
    for (int m = 0; m < 4; m++) {
        int ra = wr + m * 16 + lrow;
        int rb = wc + m * 16 + lrow;
        #pragma unroll
        for (int kk = 0; kk < 2; kk++) {
            int kc = kk * 4 + lkh;
            aof[m][kk] = ra * 64 + ((kc ^ (ra & 7)) << 3);
            bof[m][kk] = rb * 64 + ((kc ^ (rb & 7)) << 3);
        }
    }

    f32x4 acc[4][4] = {};

    // prologue: stage tile 0
    #pragma unroll
    for (int j = 0; j < 4; j++) {
        gload_lds16(ga[j], (char*)As + (wave * 4 + j) * 1024);
        gload_lds16(gb[j], (char*)Bs + (wave * 4 + j) * 1024);
    }

    for (int kt = 0; kt < NT; ++kt) {
        __syncthreads();   // drains vmcnt -> tile kt resident in LDS
        #pragma unroll
        for (int kk = 0; kk < 2; kk++) {
            bf16x8 af[4], bf_[4];
            #pragma unroll
            for (int m = 0; m < 4; m++)
                af[m] = __builtin_bit_cast(bf16x8,
                            *reinterpret_cast<const us8*>(&As[aof[m][kk]]));
            #pragma unroll
            for (int n = 0; n < 4; n++)
                bf_[n] = __builtin_bit_cast(bf16x8,
                            *reinterpret_cast<const us8*>(&Bs[bof[n][kk]]));
            #pragma unroll
            for (int m = 0; m < 4; m++)
                #pragma unroll
                for (int n = 0; n < 4; n++)
                    acc[m][n] = __builtin_amdgcn_mfma_f32_16x16x32_bf16(
                                    af[m], bf_[n], acc[m][n], 0, 0, 0);
        }
        __syncthreads();   // all waves done reading tile kt
        if (kt + 1 < NT) {
            #pragma unroll
            for (int j = 0; j < 4; j++) {
                gload_lds16(ga[j] + (kt + 1) * 64, (char*)As + (wave * 4 + j) * 1024);
                gload_lds16(gb[j] + (kt + 1) * 64, (char*)Bs + (wave * 4 + j) * 1024);
            }
        }
    }

    // epilogue
    #pragma unroll
    for (int n = 0; n < 4; n++) {
        int col = bn * 128 + wc + n * 16 + lrow;
        float bv = bias[col];
        #pragma unroll
        for (int m = 0; m < 4; m++) {
            #pragma unroll
            for (int r = 0; r < 4; r++) {
                int row = bm * 128 + wr + m * 16 + lkh * 4 + r;
                store_c<MODE>(out, extra, row, col, ldo, remap_off,
                              acc[m][n][r] + bv);
            }
        }
    }
}

// ---------------------------------------------------------------------------
// Small GEMM (N=32): direct-global fragments, compile-time K for unrolling.
// ---------------------------------------------------------------------------
template<int TN, int MODE, int K>
__global__ __launch_bounds__(256) void gemm_small(
    const unsigned short* __restrict__ A, const unsigned short* __restrict__ W,
    const float* __restrict__ bias, void* __restrict__ out,
    const float* __restrict__ extra, int N, int ldo, int remap_off)
{
    constexpr int BN = 16 * TN;
    const int tiles_n = N / BN;
    const int bm = blockIdx.x / tiles_n;
    const int bn = blockIdx.x % tiles_n;
    const int wave = threadIdx.x >> 6;
    const int lane = threadIdx.x & 63;
    const int row0 = bm * 64 + wave * 16;
    const int col0 = bn * BN;
    const int lrow = lane & 15;
    const int lk   = (lane >> 4) << 3;

    f32x4 acc[TN] = {};
    const unsigned short* ap  = A + (size_t)(row0 + lrow) * K + lk;
    const unsigned short* wp0 = W + (size_t)(col0 + lrow) * K + lk;

    #pragma unroll 4
    for (int ks = 0; ks < K; ks += 32) {
        bf16x8 af = __builtin_bit_cast(bf16x8,
                        *reinterpret_cast<const us8*>(ap + ks));
        #pragma unroll
        for (int tt = 0; tt < TN; tt++) {
            bf16x8 bfm = __builtin_bit_cast(bf16x8,
                        *reinterpret_cast<const us8*>(wp0 + (size_t)tt * 16 * K + ks));
            acc[tt] = __builtin_amdgcn_mfma_f32_16x16x32_bf16(af, bfm, acc[tt], 0, 0, 0);
        }
    }

    #pragma unroll
    for (int tt = 0; tt < TN; tt++) {
        int col = col0 + tt * 16 + lrow;
        float bv = bias[col];
        #pragma unroll
        for (int r = 0; r < 4; r++) {
            int row = row0 + (lane >> 4) * 4 + r;
            store_c<MODE>(out, extra, row, col, ldo, remap_off, acc[tt][r] + bv);
        }
    }
}

// ---------------------------------------------------------------------------
// inputs_mean = relu(ut(h_s)).mean over NS=8 rows per batch
// ---------------------------------------------------------------------------
__global__ __launch_bounds__(256) void mean_kernel(
    const unsigned short* __restrict__ UTR, float* __restrict__ MEAN)
{
    int idx = blockIdx.x * blockDim.x + threadIdx.x;   // 2048*512
    if (idx >= Bb * Hd) return;
    int b = idx >> 9, j = idx & 511;
    float s = 0.f;
    #pragma unroll
    for (int r = 0; r < 8; r++)
        s += bf2f(UTR[((size_t)(b * 8 + r) << 9) + j]);
    MEAN[idx] = s * 0.125f;
}

// kk = inputs_mean + tanh(mem)   -> bf16
__global__ __launch_bounds__(256) void kk_kernel(
    const float* __restrict__ MEAN, const float* __restrict__ mem,
    unsigned short* __restrict__ KK)
{
    int idx = blockIdx.x * blockDim.x + threadIdx.x;   // 16384*512
    int m = idx >> 9;
    int bj = ((m >> 3) << 9) + (idx & 511);
    KK[idx] = f2bf(MEAN[bj] + tanhf(mem[idx]));
}

// mem_new = sig(ig)*tanh(mem_write) + sig(fg)*mem  (gates already sigmoided)
__global__ __launch_bounds__(256) void memnew_kernel(
    const unsigned short* __restrict__ GATES, const unsigned short* __restrict__ TMW,
    const float* __restrict__ mem, float* __restrict__ out_mem,
    unsigned short* __restrict__ MNB)
{
    int idx = blockIdx.x * blockDim.x + threadIdx.x;   // 16384*512
    int m = idx >> 9, j = idx & 511;
    float ig = bf2f(GATES[(size_t)m * 1024 + j]);
    float fg = bf2f(GATES[(size_t)m * 1024 + 512 + j]);
    float v  = ig * bf2f(TMW[idx]) + fg * mem[idx];
    out_mem[idx] = v;
    MNB[idx] = f2bf(v);
}

// ---------------------------------------------------------------------------
// Attention 1: per batch, q(8,32) k(16,32) v(16,512) -> ctx(8,512) bf16
// ---------------------------------------------------------------------------
__global__ __launch_bounds__(256) void attn1_kernel(
    const float* __restrict__ Q1, const float* __restrict__ K1,
    const unsigned short* __restrict__ V1, unsigned short* __restrict__ CTX1)
{
    int b = blockIdx.x, t = threadIdx.x;
    __shared__ float q[8][32], k[16][32], pr[8][16];
    q[t >> 5][t & 31] = Q1[(size_t)b * 256 + t];
    k[t >> 5][t & 31]       = K1[(size_t)b * 512 + t];
    k[8 + (t >> 5)][t & 31] = K1[(size_t)b * 512 + 256 + t];
    __syncthreads();
    if (t < 128) {
        int s = t >> 4, tt = t & 15;
        float acc = 0.f;
        #pragma unroll
        for (int i = 0; i < 32; i++) acc += q[s][i] * k[tt][i];
        pr[s][tt] = acc * 0.17677669529663687f;   // 1/sqrt(32)
    }
    __syncthreads();
    if (t < 8) {
        float m = -1e30f;
        for (int i = 0; i < 16; i++) m = fmaxf(m, pr[t][i]);
        float e[16], sum = 0.f;
        for (int i = 0; i < 16; i++) { e[i] = expf(pr[t][i] - m); sum += e[i]; }
        float inv = 1.f / sum;
        for (int i = 0; i < 16; i++) pr[t][i] = e[i] * inv;
    }
    __syncthreads();
    int s = t >> 5, d0 = (t & 31) * 16;
    float a[16];
    #pragma unroll
    for (int i = 0; i < 16; i++) a[i] = 0.f;
    for (int tt = 0; tt < 16; tt++) {
        float p = pr[s][tt];
        const unsigned short* vp = V1 + ((size_t)(b * 16 + tt)) * 512 + d0;
        us8 v0 = *reinterpret_cast<const us8*>(vp);
        us8 v1 = *reinterpret_cast<const us8*>(vp + 8);
        #pragma unroll
        for (int i = 0; i < 8; i++) a[i]     += p * bf2f(v0[i]);
        #pragma unroll
        for (int i = 0; i < 8; i++) a[8 + i] += p * bf2f(v1[i]);
    }
    us8 o0, o1;
    #pragma unroll
    for (int i = 0; i < 8; i++) { o0[i] = f2bf(a[i]); o1[i] = f2bf(a[8 + i]); }
    unsigned short* cp = CTX1 + ((size_t)(b * 8 + s)) * 512 + d0;
    *reinterpret_cast<us8*>(cp) = o0;
    *reinterpret_cast<us8*>(cp + 8) = o1;
}

// ---------------------------------------------------------------------------
// Attention 2: per batch, 4 heads: q(8,32) k(8,32) v(8,512) -> ctx(8,2048)
// ---------------------------------------------------------------------------
__global__ __launch_bounds__(256) void attn2_kernel(
    const float* __restrict__ Q2, const float* __restrict__ K2,
    const unsigned short* __restrict__ V2, unsigned short* __restrict__ CTX2)
{
    int b = blockIdx.x, t = threadIdx.x;
    __shared__ float q[8][128], k[8][128], pr[4][8][8];
    for (int i = t; i < 1024; i += 256) {
        q[i >> 7][i & 127] = Q2[(size_t)b * 1024 + i];
        k[i >> 7][i & 127] = K2[(size_t)b * 1024 + i];
    }
    __syncthreads();
    {
        int h = t >> 6, n = (t >> 3) & 7, s = t & 7;
        float acc = 0.f;
        #pragma unroll
        for (int i = 0; i < 32; i++) acc += q[n][h * 32 + i] * k[s][h * 32 + i];
        pr[h][n][s] = acc * 0.17677669529663687f;
    }
    __syncthreads();
    if (t < 32) {
        int h = t >> 3, n = t & 7;
        float m = -1e30f;
        for (int i = 0; i < 8; i++) m = fmaxf(m, pr[h][n][i]);
        float e[8], sum = 0.f;
        for (int i = 0; i < 8; i++) { e[i] = expf(pr[h][n][i] - m); sum += e[i]; }
        float inv = 1.f / sum;
        for (int i = 0; i < 8; i++) pr[h][n][i] = e[i] * inv;
    }
    __syncthreads();
    int n = t >> 5, d0 = (t & 31) * 16;
    for (int h = 0; h < 4; h++) {
        float a[16];
        #pragma unroll
        for (int i = 0; i < 16; i++) a[i] = 0.f;
        for (int s = 0; s < 8; s++) {
            float p = pr[h][n][s];
            const unsigned short* vp = V2 + ((size_t)(b * 8 + s)) * 2048 + h * 512 + d0;
            us8 v0 = *reinterpret_cast<const us8*>(vp);
            us8 v1 = *reinterpret_cast<const us8*>(vp + 8);
            #pragma unroll
            for (int i = 0; i < 8; i++) a[i]     += p * bf2f(v0[i]);
            #pragma unroll
            for (int i = 0; i < 8; i++) a[8 + i] += p * bf2f(v1[i]);
        }
        us8 o0, o1;
        #pragma unroll
        for (int i = 0; i < 8; i++) { o0[i] = f2bf(a[i]); o1[i] = f2bf(a[8 + i]); }
        unsigned short* cp = CTX2 + ((size_t)(b * 8 + n)) * 2048 + h * 512 + d0;
        *reinterpret_cast<us8*>(cp) = o0;
        *reinterpret_cast<us8*>(cp + 8) = o1;
    }
}

// ---------------------------------------------------------------------------
extern "C" void kernel_launch(void* const* d_in, const int* in_sizes, int n_in,
                              void* d_out, int out_size, void* d_ws, size_t ws_size,
                              hipStream_t stream)
{
    const float* h_s  = (const float*)d_in[0];
    const float* mem  = (const float*)d_in[1];
    const float* wq_w = (const float*)d_in[2];  const float* wq_b = (const float*)d_in[3];
    const float* wk_w = (const float*)d_in[4];  const float* wk_b = (const float*)d_in[5];
    const float* wv_w = (const float*)d_in[6];  const float* wv_b = (const float*)d_in[7];
    const float* wo_w = (const float*)d_in[8];  const float* wo_b = (const float*)d_in[9];
    const float* ut_w = (const float*)d_in[10]; const float* ut_b = (const float*)d_in[11];
    const float* ug_w = (const float*)d_in[12]; const float* ug_b = (const float*)d_in[13];
    const float* rq_w = (const float*)d_in[14]; const float* rq_b = (const float*)d_in[15];
    const float* rk_w = (const float*)d_in[16]; const float* rk_b = (const float*)d_in[17];
    const float* rv_w = (const float*)d_in[18]; const float* rv_b = (const float*)d_in[19];
    const float* ro_w = (const float*)d_in[20]; const float* ro_b = (const float*)d_in[21];

    char* ws = (char*)d_ws;
    unsigned short* WQb = (unsigned short*)(ws + OFF_WQ);
    unsigned short* WKb = (unsigned short*)(ws + OFF_WK);
    unsigned short* WVb = (unsigned short*)(ws + OFF_WV);
    unsigned short* WOb = (unsigned short*)(ws + OFF_WO);
    unsigned short* UTb = (unsigned short*)(ws + OFF_UT);
    unsigned short* UGb = (unsigned short*)(ws + OFF_UG);
    unsigned short* RQb = (unsigned short*)(ws + OFF_RQ);
    unsigned short* RKb = (unsigned short*)(ws + OFF_RK);
    unsigned short* RVb = (unsigned short*)(ws + OFF_RV);
    unsigned short* ROb = (unsigned short*)(ws + OFF_RO);
    unsigned short* HSb  = (unsigned short*)(ws + OFF_HS);
    unsigned short* MEMb = (unsigned short*)(ws + OFF_MEM);
    unsigned short* UTR  = (unsigned short*)(ws + OFF_UTR);
    float*          MEAN = (float*)(ws + OFF_MEAN);
    float*          Q1   = (float*)(ws + OFF_Q1);
    float*          K1   = (float*)(ws + OFF_K1);
    unsigned short* V1   = (unsigned short*)(ws + OFF_V1);
    unsigned short* CTX1 = (unsigned short*)(ws + OFF_CTX1);
    unsigned short* KKb  = (unsigned short*)(ws + OFF_KK);
    unsigned short* TMW  = (unsigned short*)(ws + OFF_TMW);
    unsigned short* GATES= (unsigned short*)(ws + OFF_GATES);
    unsigned short* MNB  = (unsigned short*)(ws + OFF_MNB);
    float*          Q2   = (float*)(ws + OFF_Q2);
    float*          K2   = (float*)(ws + OFF_K2);
    unsigned short* RVO  = (unsigned short*)(ws + OFF_RVO);
    unsigned short* CTX2 = (unsigned short*)(ws + OFF_CTX2);

    float* out   = (float*)d_out;            // h_out (16384,512)
    float* out_m = out + (size_t)Mrows * Hd; // mem_new (16384,512)

    // 1) cast inputs + weights to bf16
    CastParams cp;
    cp.seg[0]  = { h_s,  HSb,  (Mrows * Hd) / 4 };
    cp.seg[1]  = { mem,  MEMb, (Mrows * Hd) / 4 };
    cp.seg[2]  = { wq_w, WQb,  (32 * 512) / 4 };
    cp.seg[3]  = { wk_w, WKb,  (32 * 512) / 4 };
    cp.seg[4]  = { wv_w, WVb,  (512 * 512) / 4 };
    cp.seg[5]  = { wo_w, WOb,  (512 * 512) / 4 };
    cp.seg[6]  = { ut_w, UTb,  (512 * 512) / 4 };
    cp.seg[7]  = { ug_w, UGb,  (1024 * 512) / 4 };
    cp.seg[8]  = { rq_w, RQb,  (128 * 512) / 4 };
    cp.seg[9]  = { rk_w, RKb,  (128 * 512) / 4 };
    cp.seg[10] = { rv_w, RVb,  (2048 * 512) / 4 };
    cp.seg[11] = { ro_w, ROb,  (512 * 2048) / 4 };
    cast_all<<<dim3(2048, 12), 256, 0, stream>>>(cp);

    // 2) stage-1 GEMMs (depend only on h_s / mem)
    gemm_big<512,2><<<512,  256, 0, stream>>>(HSb,  UTb, ut_b, UTR, nullptr, 512, 512, 0);
    gemm_big<512,0><<<128,  256, 0, stream>>>(HSb,  RQb, rq_b, Q2,  nullptr, 128, 128, 0);
    gemm_small<2,5,512><<<256, 256, 0, stream>>>(HSb, WKb, wk_b, K1, nullptr, 32, 32, 0);
    gemm_big<512,6><<<512,  256, 0, stream>>>(HSb,  WVb, wv_b, V1,  nullptr, 512, 512, 0);
    gemm_small<2,0,512><<<256, 256, 0, stream>>>(MEMb, WQb, wq_b, Q1, nullptr, 32, 32, 0);
    gemm_small<2,5,512><<<256, 256, 0, stream>>>(MEMb, WKb, wk_b, K1, nullptr, 32, 32, 8);
    gemm_big<512,6><<<512,  256, 0, stream>>>(MEMb, WVb, wv_b, V1,  nullptr, 512, 512, 8);

    // 3) mean + kk
    mean_kernel<<<4096, 256, 0, stream>>>(UTR, MEAN);
    kk_kernel<<<32768, 256, 0, stream>>>(MEAN, mem, KKb);

    // 4) attention 1 -> ctx1
    attn1_kernel<<<Bb, 256, 0, stream>>>(Q1, K1, V1, CTX1);

    // 5) wo (-> tanh(mem_write)) and ug (-> sigmoid gates)
    gemm_big<512,4><<<512,  256, 0, stream>>>(CTX1, WOb, wo_b, TMW,   nullptr,  512,  512, 0);
    gemm_big<512,3><<<1024, 256, 0, stream>>>(KKb,  UGb, ug_b, GATES, nullptr, 1024, 1024, 0);

    // 6) mem_new (writes d_out second half + bf16 copy)
    memnew_kernel<<<32768, 256, 0, stream>>>(GATES, TMW, mem, out_m, MNB);

    // 7) rk, rv on mem_new
    gemm_big<512,0><<<128,  256, 0, stream>>>(MNB, RKb, rk_b, K2,  nullptr,  128,  128, 0);
    gemm_big<512,1><<<2048, 256, 0, stream>>>(MNB, RVb, rv_b, RVO, nullptr, 2048, 2048, 0);

    // 8) attention 2 -> ctx2
    attn2_kernel<<<Bb, 256, 0, stream>>>(Q2, K2, RVO, CTX2);

    // 9) ro + residual -> h_out (d_out first half)
    gemm_big<2048,7><<<512, 256, 0, stream>>>(CTX2, ROb, ro_b, out, h_s, 512, 512, 0);

    (void)in_sizes; (void)n_in; (void)out_size; (void)ws_size;
}